// Round 1
// baseline (331.503 us; speedup 1.0000x reference)
//
#include <hip/hip_runtime.h>
#include <hip/hip_bf16.h>

// Problem constants
#define BB 8
#define CC 128
#define NN 16384            // 128*128 tokens per batch
#define MM (BB * NN)        // 131072
#define NCH 64              // scan chunks
#define CLN 256             // chunk length (NN / NCH)

typedef __attribute__((ext_vector_type(8))) short short8;   // 8 x bf16 (4 VGPRs)
typedef __attribute__((ext_vector_type(4))) float floatx4;  // MFMA accumulator
typedef unsigned short u16;
typedef unsigned int u32;

__device__ __forceinline__ float bf2f(u16 h) {
  u32 u = ((u32)h) << 16;
  return __builtin_bit_cast(float, u);
}
__device__ __forceinline__ u16 f2bf(float f) {
  u32 u = __builtin_bit_cast(u32, f);
  u32 r = u + 0x7FFFu + ((u >> 16) & 1u);   // round-to-nearest-even
  return (u16)(r >> 16);
}

// ---------------------------------------------------------------------------
// FiLM params: gamma[b,c] = gs[b,:]·cond_gw[c,:] + cond_gb[c]; beta likewise.
__global__ void film_kernel(const float* __restrict__ gs, const float* __restrict__ gw,
                            const float* __restrict__ gb, const float* __restrict__ bw,
                            const float* __restrict__ bb, float* __restrict__ gamma,
                            float* __restrict__ beta) {
  int idx = blockIdx.x * 256 + threadIdx.x;   // 0..1023
  int b = idx >> 7, c = idx & 127;
  float sg = 0.f, sb = 0.f;
  for (int j = 0; j < 128; ++j) {
    float g = gs[b * 128 + j];
    sg += g * gw[c * 128 + j];
    sb += g * bw[c * 128 + j];
  }
  gamma[idx] = sg + gb[c];
  beta[idx] = sb + bb[c];
}

// ---------------------------------------------------------------------------
// Convert all 6 weight tensors (each (2,128,128) f32) to bf16, packed
// [which][block][o][c] at dst + which*32768.
__global__ void convert_kernel(const float* __restrict__ Wk, const float* __restrict__ Wv,
                               const float* __restrict__ Wr, const float* __restrict__ Wo,
                               const float* __restrict__ gp, const float* __restrict__ bp,
                               u16* __restrict__ dst) {
  int idx = blockIdx.x * 256 + threadIdx.x;   // 0..196607
  int which = idx >> 15;
  int off = idx & 32767;
  const float* s;
  switch (which) {
    case 0: s = Wk; break; case 1: s = Wv; break; case 2: s = Wr; break;
    case 3: s = Wo; break; case 4: s = gp; break; default: s = bp; break;
  }
  dst[idx] = f2bf(s[off]);
}

// ---------------------------------------------------------------------------
// Prep: (UPS=1) bilinear 2x upsample + write x_up to out(BCHW) + FiLM + LN -> xn bf16
//       (UPS=0) read out(BCHW) + LN -> xn bf16
// One block = 64 tokens (half a row ho), transposed through LDS.
template <int UPS>
__global__ __launch_bounds__(256) void prep_kernel(
    const float* __restrict__ src, const float* __restrict__ gamma,
    const float* __restrict__ beta, const float* __restrict__ lng,
    const float* __restrict__ lnb, float* __restrict__ outp, u16* __restrict__ xn) {
  __shared__ float tile[64][129];
  __shared__ float smu[64], srs[64];
  int bidx = blockIdx.x;              // 0..2047
  int half = bidx & 1;
  int ho = (bidx >> 1) & 127;
  int b = bidx >> 8;
  int wo0 = half * 64;
  int tid = threadIdx.x;
  int tk = tid & 63;
  int wo = wo0 + tk;
  int c0 = tid >> 6;                  // 0..3
  int j0 = 0, j1 = 0, i0 = 0, i1 = 0;
  float wy0 = 0.f, wy1 = 0.f, wx0 = 0.f, wx1 = 0.f;
  if (UPS) {
    int jj = ho >> 1;
    if ((ho & 1) == 0) { j0 = jj > 0 ? jj - 1 : 0; j1 = jj; wy0 = 0.25f; wy1 = 0.75f; }
    else               { j0 = jj; j1 = jj < 63 ? jj + 1 : 63; wy0 = 0.75f; wy1 = 0.25f; }
    int ii = wo >> 1;
    if ((wo & 1) == 0) { i0 = ii > 0 ? ii - 1 : 0; i1 = ii; wx0 = 0.25f; wx1 = 0.75f; }
    else               { i0 = ii; i1 = ii < 63 ? ii + 1 : 63; wx0 = 0.75f; wx1 = 0.25f; }
  }
  for (int it = 0; it < 32; ++it) {
    int c = it * 4 + c0;
    float v;
    if (UPS) {
      const float* xp = src + ((size_t)(b * 128 + c)) * 4096;
      v = wy0 * (wx0 * xp[j0 * 64 + i0] + wx1 * xp[j0 * 64 + i1]) +
          wy1 * (wx0 * xp[j1 * 64 + i0] + wx1 * xp[j1 * 64 + i1]);
      outp[((size_t)(b * 128 + c)) * 16384 + ho * 128 + wo] = v;
      v = v * (1.f + gamma[b * 128 + c]) + beta[b * 128 + c];
    } else {
      v = src[((size_t)(b * 128 + c)) * 16384 + ho * 128 + wo];
    }
    tile[tk][c] = v;
  }
  __syncthreads();
  {
    int token = tid >> 2, q = tid & 3;
    float s = 0.f, s2 = 0.f;
    for (int j = 0; j < 32; ++j) { float v = tile[token][q * 32 + j]; s += v; s2 += v * v; }
    s += __shfl_xor(s, 1); s2 += __shfl_xor(s2, 1);
    s += __shfl_xor(s, 2); s2 += __shfl_xor(s2, 2);
    if (q == 0) {
      float mu = s * 0.0078125f;
      float var = s2 * 0.0078125f - mu * mu;
      smu[token] = mu;
      srs[token] = rsqrtf(var + 1e-5f);
    }
  }
  __syncthreads();
  size_t base = ((size_t)b * 16384 + ho * 128 + wo0) * 128;
  for (int it = 0; it < 32; ++it) {
    int idx = it * 256 + tid;
    int token = idx >> 7, c = idx & 127;
    float v = (tile[token][c] - smu[token]) * srs[token] * lng[c] + lnb[c];
    xn[base + idx] = f2bf(v);
  }
}

// ---------------------------------------------------------------------------
// Row-major-output GEMM: out[m, o] = sum_c A[m,c] * W[o,c].
// MODE 0: three weights -> k (f32), v (bf16), r (sigmoid, bf16).
// MODE 1: one weight -> outV bf16.
// 256 thr / 4 waves, tile M=128, full N=128, K=128. XOR-swizzled LDS (no pad).
template <int MODE>
__global__ __launch_bounds__(256) void gemm_rowout_kernel(
    const u16* __restrict__ A, const u16* __restrict__ W0, const u16* __restrict__ W1,
    const u16* __restrict__ W2, float* __restrict__ outK, u16* __restrict__ outV,
    u16* __restrict__ outR) {
  __shared__ u16 Alds[128 * 128];
  __shared__ u16 Wlds[128 * 128];
  int tid = threadIdx.x;
  int wave = tid >> 6, lane = tid & 63;
  int l15 = lane & 15, l4 = lane >> 4;
  size_t row0 = (size_t)blockIdx.x * 128;
#pragma unroll
  for (int it = 0; it < 8; ++it) {
    int idx = it * 256 + tid;
    int r = idx >> 4, s = idx & 15;
    uint4 d = *(const uint4*)(A + (row0 + r) * 128 + s * 8);
    *(uint4*)(&Alds[r * 128 + ((s ^ (r & 15)) << 3)]) = d;
  }
  const u16* Wsarr[3] = {W0, W1, W2};
  const int NW = (MODE == 0) ? 3 : 1;
#pragma unroll
  for (int wsi = 0; wsi < NW; ++wsi) {
#pragma unroll
    for (int it = 0; it < 8; ++it) {
      int idx = it * 256 + tid;
      int r = idx >> 4, s = idx & 15;
      uint4 d = *(const uint4*)(Wsarr[wsi] + r * 128 + s * 8);
      *(uint4*)(&Wlds[r * 128 + ((s ^ (r & 15)) << 3)]) = d;
    }
    __syncthreads();
    floatx4 acc[2][8];
#pragma unroll
    for (int mi = 0; mi < 2; ++mi)
#pragma unroll
      for (int ni = 0; ni < 8; ++ni) acc[mi][ni] = (floatx4){0.f, 0.f, 0.f, 0.f};
#pragma unroll
    for (int kk = 0; kk < 4; ++kk) {
      int seg = kk * 4 + l4;
      short8 a0 = *(const short8*)(&Alds[(wave * 32 + l15) * 128 + ((seg ^ l15) << 3)]);
      short8 a1 = *(const short8*)(&Alds[(wave * 32 + 16 + l15) * 128 + ((seg ^ l15) << 3)]);
#pragma unroll
      for (int ni = 0; ni < 8; ++ni) {
        short8 bfr = *(const short8*)(&Wlds[(ni * 16 + l15) * 128 + ((seg ^ l15) << 3)]);
        acc[0][ni] = __builtin_amdgcn_mfma_f32_16x16x32_bf16(a0, bfr, acc[0][ni], 0, 0, 0);
        acc[1][ni] = __builtin_amdgcn_mfma_f32_16x16x32_bf16(a1, bfr, acc[1][ni], 0, 0, 0);
      }
    }
#pragma unroll
    for (int mi = 0; mi < 2; ++mi) {
#pragma unroll
      for (int ni = 0; ni < 8; ++ni) {
        int col = ni * 16 + l15;
#pragma unroll
        for (int j = 0; j < 4; ++j) {
          size_t row = row0 + wave * 32 + mi * 16 + l4 * 4 + j;
          float val = acc[mi][ni][j];
          if (MODE == 0) {
            if (wsi == 0) outK[row * 128 + col] = val;
            else if (wsi == 1) outV[row * 128 + col] = f2bf(val);
            else outR[row * 128 + col] = f2bf(1.f / (1.f + __expf(-val)));
          } else {
            outV[row * 128 + col] = f2bf(val);
          }
        }
      }
    }
    __syncthreads();
  }
}

// ---------------------------------------------------------------------------
// Scan phase 1: per chunk, S = local state from zero init (64 chunks x 8 b x 128 c).
__global__ __launch_bounds__(256) void scan1_kernel(const float* __restrict__ k,
                                                    const float* __restrict__ td,
                                                    float* __restrict__ S) {
  int tid = blockIdx.x * 256 + threadIdx.x;   // 65536
  int c = tid & 127;
  int b = (tid >> 7) & 7;
  int chunk = tid >> 10;
  float d = __expf(-fmaxf(td[c], 0.f));
  const float* kp = k + ((size_t)b * 16384 + chunk * 256) * 128 + c;
  float s = 0.f;
#pragma unroll 16
  for (int t = 0; t < CLN; ++t) s = s * d + kp[(size_t)t * 128];
  S[chunk * 1024 + b * 128 + c] = s;
}

// Scan phase 2: wave-wide (64-lane) segment scan over chunks -> exclusive init states.
__global__ __launch_bounds__(256) void scan2_kernel(const float* __restrict__ S,
                                                    const float* __restrict__ td,
                                                    float* __restrict__ init) {
  int wave = threadIdx.x >> 6, lane = threadIdx.x & 63;
  int bc = blockIdx.x * 4 + wave;   // 0..1023
  int c = bc & 127;
  float a = __expf(-fmaxf(td[c], 0.f) * 256.f);   // decay^CLN
  float s = S[lane * 1024 + bc];
  for (int off = 1; off < 64; off <<= 1) {
    float sp = __shfl_up(s, off);
    float ap = __shfl_up(a, off);
    if (lane >= off) { s = s + a * sp; a = a * ap; }
  }
  float e = __shfl_up(s, 1);
  if (lane == 0) e = 0.f;
  init[lane * 1024 + bc] = e;
}

// Scan phase 3: replay each chunk with its true init; y = r*(state+v), bf16 over v.
__global__ __launch_bounds__(256) void scan3_kernel(const float* __restrict__ k,
                                                    u16* __restrict__ v,
                                                    const u16* __restrict__ r,
                                                    const float* __restrict__ init,
                                                    const float* __restrict__ td) {
  int tid = blockIdx.x * 256 + threadIdx.x;
  int c = tid & 127;
  int b = (tid >> 7) & 7;
  int chunk = tid >> 10;
  float d = __expf(-fmaxf(td[c], 0.f));
  float s = init[chunk * 1024 + b * 128 + c];
  size_t base = ((size_t)b * 16384 + chunk * 256) * 128 + c;
  const float* kp = k + base;
  u16* vp = v + base;
  const u16* rp = r + base;
#pragma unroll 8
  for (int t = 0; t < CLN; ++t) {
    size_t o = (size_t)t * 128;
    s = s * d + kp[o];
    float vv = bf2f(vp[o]);
    float rv = bf2f(rp[o]);
    vp[o] = f2bf(rv * (s + vv));
  }
}

// ---------------------------------------------------------------------------
// Blend: g = t@gp^T+gpb, bt = t@bp^T+bpb, out = out*(1+tanh(g)) + bt.
// Transposed orientation (A=weight rows o, B=t^T cols tokens) so D matches BCHW.
// 512 thr / 8 waves: wave = (o 32) x (tok 64).
__global__ __launch_bounds__(512) void blend_kernel(
    const u16* __restrict__ t, const u16* __restrict__ Wg, const u16* __restrict__ Wb,
    const float* __restrict__ gpb, const float* __restrict__ bpb,
    float* __restrict__ outp) {
  __shared__ u16 T[128 * 128];
  int tid = threadIdx.x;
  int b = blockIdx.x >> 7;
  int tok0 = (blockIdx.x & 127) * 128;
#pragma unroll
  for (int it = 0; it < 4; ++it) {
    int idx = it * 512 + tid;
    int r = idx >> 4, s = idx & 15;
    uint4 d = *(const uint4*)(t + ((size_t)(b * 16384 + tok0 + r)) * 128 + s * 8);
    *(uint4*)(&T[r * 128 + ((s ^ (r & 15)) << 3)]) = d;
  }
  int wave = tid >> 6, lane = tid & 63;
  int l15 = lane & 15, l4 = lane >> 4;
  int ob = (wave & 3) * 32;
  int tb = (wave >> 2) * 64;
  short8 wg[2][4], wb2[2][4];
#pragma unroll
  for (int mi = 0; mi < 2; ++mi)
#pragma unroll
    for (int kk = 0; kk < 4; ++kk) {
      int o = ob + mi * 16 + l15;
      wg[mi][kk] = *(const short8*)(Wg + o * 128 + kk * 32 + l4 * 8);
      wb2[mi][kk] = *(const short8*)(Wb + o * 128 + kk * 32 + l4 * 8);
    }
  __syncthreads();
  floatx4 ag[2][4], ab[2][4];
#pragma unroll
  for (int mi = 0; mi < 2; ++mi)
#pragma unroll
    for (int ni = 0; ni < 4; ++ni) {
      ag[mi][ni] = (floatx4){0.f, 0.f, 0.f, 0.f};
      ab[mi][ni] = (floatx4){0.f, 0.f, 0.f, 0.f};
    }
#pragma unroll
  for (int kk = 0; kk < 4; ++kk) {
    int seg = kk * 4 + l4;
#pragma unroll
    for (int ni = 0; ni < 4; ++ni) {
      short8 tf = *(const short8*)(&T[(tb + ni * 16 + l15) * 128 + ((seg ^ l15) << 3)]);
#pragma unroll
      for (int mi = 0; mi < 2; ++mi) {
        ag[mi][ni] = __builtin_amdgcn_mfma_f32_16x16x32_bf16(wg[mi][kk], tf, ag[mi][ni], 0, 0, 0);
        ab[mi][ni] = __builtin_amdgcn_mfma_f32_16x16x32_bf16(wb2[mi][kk], tf, ab[mi][ni], 0, 0, 0);
      }
    }
  }
#pragma unroll
  for (int mi = 0; mi < 2; ++mi) {
#pragma unroll
    for (int ni = 0; ni < 4; ++ni) {
      int tok = tok0 + tb + ni * 16 + l15;
#pragma unroll
      for (int j = 0; j < 4; ++j) {
        int o = ob + mi * 16 + l4 * 4 + j;
        size_t addr = ((size_t)(b * 128 + o)) * 16384 + tok;
        float g = ag[mi][ni][j] + gpb[o];
        float bt = ab[mi][ni][j] + bpb[o];
        float prev = outp[addr];
        outp[addr] = prev * (1.f + tanhf(g)) + bt;
      }
    }
  }
}

// ---------------------------------------------------------------------------
extern "C" void kernel_launch(void* const* d_in, const int* in_sizes, int n_in,
                              void* d_out, int out_size, void* d_ws, size_t ws_size,
                              hipStream_t stream) {
  const float* x        = (const float*)d_in[0];
  const float* gs       = (const float*)d_in[1];
  const float* cond_gw  = (const float*)d_in[2];
  const float* cond_gb  = (const float*)d_in[3];
  const float* cond_bw  = (const float*)d_in[4];
  const float* cond_bb  = (const float*)d_in[5];
  const float* td       = (const float*)d_in[6];
  const float* Wk       = (const float*)d_in[7];
  const float* Wv       = (const float*)d_in[8];
  const float* Wr       = (const float*)d_in[9];
  const float* Wo       = (const float*)d_in[10];
  const float* ln_g     = (const float*)d_in[11];
  const float* ln_b     = (const float*)d_in[12];
  const float* gp_w     = (const float*)d_in[13];
  const float* gp_b     = (const float*)d_in[14];
  const float* bp_w     = (const float*)d_in[15];
  const float* bp_b     = (const float*)d_in[16];
  float* outp = (float*)d_out;

  char* w = (char*)d_ws;
  float* gamma = (float*)w; w += 4096;
  float* beta  = (float*)w; w += 4096;
  u16* wbf     = (u16*)w;   w += 6 * 2 * 16384 * sizeof(u16);     // 384 KB
  u16* xn      = (u16*)w;   w += (size_t)MM * 128 * sizeof(u16);  // 32 MB (also t)
  float* kbuf  = (float*)w; w += (size_t)MM * 128 * sizeof(float);// 64 MB
  u16* vbuf    = (u16*)w;   w += (size_t)MM * 128 * sizeof(u16);  // 32 MB (also y)
  u16* rbuf    = (u16*)w;   w += (size_t)MM * 128 * sizeof(u16);  // 32 MB
  float* Sbuf  = (float*)w; w += NCH * 1024 * sizeof(float);
  float* ibuf  = (float*)w; w += NCH * 1024 * sizeof(float);

  film_kernel<<<4, 256, 0, stream>>>(gs, cond_gw, cond_gb, cond_bw, cond_bb, gamma, beta);
  convert_kernel<<<768, 256, 0, stream>>>(Wk, Wv, Wr, Wo, gp_w, bp_w, wbf);

  for (int blk = 0; blk < 2; ++blk) {
    const u16* bWk = wbf + 0 * 32768 + blk * 16384;
    const u16* bWv = wbf + 1 * 32768 + blk * 16384;
    const u16* bWr = wbf + 2 * 32768 + blk * 16384;
    const u16* bWo = wbf + 3 * 32768 + blk * 16384;
    const u16* bGp = wbf + 4 * 32768 + blk * 16384;
    const u16* bBp = wbf + 5 * 32768 + blk * 16384;
    const float* tdi = td + blk * 128;

    if (blk == 0)
      prep_kernel<1><<<2048, 256, 0, stream>>>(x, gamma, beta, ln_g, ln_b, outp, xn);
    else
      prep_kernel<0><<<2048, 256, 0, stream>>>(outp, nullptr, nullptr, ln_g + 128,
                                               ln_b + 128, nullptr, xn);

    gemm_rowout_kernel<0><<<1024, 256, 0, stream>>>(xn, bWk, bWv, bWr, kbuf, vbuf, rbuf);
    scan1_kernel<<<256, 256, 0, stream>>>(kbuf, tdi, Sbuf);
    scan2_kernel<<<256, 256, 0, stream>>>(Sbuf, tdi, ibuf);
    scan3_kernel<<<256, 256, 0, stream>>>(kbuf, vbuf, rbuf, ibuf, tdi);
    gemm_rowout_kernel<1><<<1024, 256, 0, stream>>>(vbuf, bWo, nullptr, nullptr,
                                                    nullptr, xn, nullptr);
    blend_kernel<<<1024, 512, 0, stream>>>(xn, bGp, bBp, gp_b + blk * 128,
                                           bp_b + blk * 128, outp);
  }
}